// Round 7
// baseline (159.216 us; speedup 1.0000x reference)
//
#include <hip/hip_runtime.h>
#include <hip/hip_bf16.h>
#include <stdint.h>

// Problem constants (B, L, D, T) = (2, 2048, 1536, 2)
#define B_ 2
#define L_ 2048
#define D_ 1536

typedef __attribute__((ext_vector_type(4))) float  f32x4;
typedef __attribute__((ext_vector_type(8))) __bf16 bf16x8;

__device__ __forceinline__ unsigned short f2bf(float f) {
  unsigned int u = __float_as_uint(f);
  u += 0x7fffu + ((u >> 16) & 1u);   // RNE
  return (unsigned short)(u >> 16);
}

// Stage 1: hs(fp32) -> X(bf16), and P[t] = hs * Wp[t] (bf16), t in {0,1}
__global__ __launch_bounds__(256) void conv_kernel(
    const float* __restrict__ hs, const float* __restrict__ W,
    unsigned short* __restrict__ X, unsigned short* __restrict__ P) {
  const int idx  = blockIdx.x * 256 + threadIdx.x;
  const int base = idx * 4;                       // 4 consecutive d per thread
  const int d    = base % D_;                     // row-major (b,i,d); D_%4==0
  const float4 h  = *(const float4*)(hs + base);
  const float4 w0 = *(const float4*)(W + d);            // Wp[0, d..d+3]
  const float4 w1 = *(const float4*)(W + 2 * D_ + d);   // Wp[1, d..d+3]
  ushort4 x, p0, p1;
  x.x  = f2bf(h.x);        x.y  = f2bf(h.y);        x.z  = f2bf(h.z);        x.w  = f2bf(h.w);
  p0.x = f2bf(h.x * w0.x); p0.y = f2bf(h.y * w0.y); p0.z = f2bf(h.z * w0.z); p0.w = f2bf(h.w * w0.w);
  p1.x = f2bf(h.x * w1.x); p1.y = f2bf(h.y * w1.y); p1.z = f2bf(h.z * w1.z); p1.w = f2bf(h.w * w1.w);
  *(ushort4*)(X + base) = x;
  *(ushort4*)(P + base) = p0;
  *(ushort4*)(P + (size_t)B_ * L_ * D_ + base) = p1;
}

// Stage 2 (t-defused, reg-staged pipeline):
// out[b,i,j,t] = P_t[b,i,:].X[b,j,:] + bias[t]
// Grid 1024, 256 threads, 128x128, BK=32, double-buffered LDS (32 KB).
// Staging: global_load_dwordx4 -> VGPR -> ds_write_b128, prefetch distance
// one full K-iter (barrier waits lgkm only, never vmcnt(0) -- R6 lesson).
// t de-fused into grid for 3 blocks/CU (12 waves/CU latency hiding);
// t-pairs of one (b,i,j) tile sit 8 ids apart (same XCD) so their
// interleaved stride-2 stores merge in that XCD's L2 (R2 measured 84 MB).
__global__ __launch_bounds__(256, 3) void gemm_kernel(
    const unsigned short* __restrict__ X, const unsigned short* __restrict__ P,
    const float* __restrict__ bias, float* __restrict__ out) {
  __shared__ unsigned short As[2 * 128 * 32];
  __shared__ unsigned short Bs[2 * 128 * 32];

  const int tid = threadIdx.x;

  // ---- block-id decode: id = xcd + 8*(t + 2*(within + 16*pp))
  const int id     = blockIdx.x;
  const int xcd    = id & 7;
  const int u      = id >> 3;
  const int t      = u & 1;
  const int v      = u >> 1;          // 0..63
  const int within = v & 15;          // position in 4x4 tile patch
  const int pp     = v >> 4;          // 0..3
  const int Pp     = pp * 8 + xcd;    // patch 0..31 (16 per b)
  const int bz     = Pp >> 4;
  const int pr     = Pp & 15;
  const int I0     = ((pr >> 2) * 4 + (within >> 2)) * 128;
  const int J0     = ((pr & 3)  * 4 + (within & 3))  * 128;

  // ---- staging geometry: thread tid fills slot (row=tid>>2, slot=tid&3),
  // 16B per thread. XOR swizzle in the GLOBAL address: slot cs holds global
  // chunk gc = cs ^ ((row>>1)&3); LDS side stays linear (ldst = tid*8).
  const int srow = tid >> 2;
  const int cs   = tid & 3;
  const int gc   = cs ^ ((srow >> 1) & 3);
  const int scol = gc * 8;
  const int ldst = tid * 8;

  const unsigned short* pA =
      P + (size_t)t * B_ * L_ * D_ + ((size_t)(bz * L_ + I0 + srow)) * D_ + scol;
  const unsigned short* pB = X + ((size_t)(bz * L_ + J0 + srow)) * D_ + scol;

  // ---- compute geometry (2x2 waves of 64x64)
  const int lane = tid & 63;
  const int w    = tid >> 6;
  const int wi   = (w & 1) * 64;
  const int wj   = (w >> 1) * 64;
  const int lr   = lane & 15;
  const int q    = lane >> 4;
  const int ccol = (q ^ ((lr >> 1) & 3)) * 8;    // read-side swizzle

  int aoff[4], boff[4];
#pragma unroll
  for (int m = 0; m < 4; ++m) {
    aoff[m] = (wi + m * 16 + lr) * 32 + ccol;
    boff[m] = (wj + m * 16 + lr) * 32 + ccol;
  }

  f32x4 acc[4][4] = {};

  uint4 ral, rah, rbl, rbh;   // reg set 0
  uint4 sal, sah, sbl, sbh;   // reg set 1

#define GLOAD0(koff)                                \
  do {                                              \
    ral = *(const uint4*)(pA + (koff));             \
    rah = *(const uint4*)(pA + (koff) + 64 * D_);   \
    rbl = *(const uint4*)(pB + (koff));             \
    rbh = *(const uint4*)(pB + (koff) + 64 * D_);   \
  } while (0)
#define GLOAD1(koff)                                \
  do {                                              \
    sal = *(const uint4*)(pA + (koff));             \
    sah = *(const uint4*)(pA + (koff) + 64 * D_);   \
    sbl = *(const uint4*)(pB + (koff));             \
    sbh = *(const uint4*)(pB + (koff) + 64 * D_);   \
  } while (0)
#define DSW(buf, AL, AH, BL, BH)                    \
  do {                                              \
    *(uint4*)(As + (buf) * 4096 + ldst)        = AL;\
    *(uint4*)(As + (buf) * 4096 + ldst + 2048) = AH;\
    *(uint4*)(Bs + (buf) * 4096 + ldst)        = BL;\
    *(uint4*)(Bs + (buf) * 4096 + ldst + 2048) = BH;\
  } while (0)
#define COMPUTE(buf)                                                          \
  do {                                                                        \
    const unsigned short* Ab = As + (buf) * 4096;                             \
    const unsigned short* Bb = Bs + (buf) * 4096;                             \
    bf16x8 af[4], bf_[4];                                                     \
    _Pragma("unroll") for (int m = 0; m < 4; ++m)                             \
      af[m] = *(const bf16x8*)(Ab + aoff[m]);                                 \
    _Pragma("unroll") for (int n = 0; n < 4; ++n)                             \
      bf_[n] = *(const bf16x8*)(Bb + boff[n]);                                \
    _Pragma("unroll") for (int m = 0; m < 4; ++m)                             \
      _Pragma("unroll") for (int n = 0; n < 4; ++n)                           \
        acc[m][n] = __builtin_amdgcn_mfma_f32_16x16x32_bf16(af[m], bf_[n],    \
                                                            acc[m][n], 0, 0, 0); \
  } while (0)

  GLOAD0(0);
  for (int k = 0; k < D_ / 32; k += 2) {
    // iter k: publish r-set to buf0, prefetch k+1 into s-set
    DSW(0, ral, rah, rbl, rbh);
    GLOAD1((k + 1) * 32);                     // k+1 <= 47 always
    __syncthreads();                          // lgkm drain only (no vmcnt)
    COMPUTE(0);
    // iter k+1: publish s-set to buf1, prefetch k+2 into r-set
    DSW(1, sal, sah, sbl, sbh);
    if (k + 2 < D_ / 32) GLOAD0((k + 2) * 32);
    __syncthreads();
    COMPUTE(1);
  }
#undef GLOAD0
#undef GLOAD1
#undef DSW
#undef COMPUTE

  // ---- epilogue: C/D layout col(j)=lane&15, row(i)=quad*4+reg
  const float bt = bias[t];
#pragma unroll
  for (int m = 0; m < 4; ++m) {
#pragma unroll
    for (int r = 0; r < 4; ++r) {
      const int i = I0 + wi + m * 16 + q * 4 + r;
      float* orow = out + (((size_t)(bz * L_ + i)) * L_ + (J0 + wj + lr)) * 2 + t;
#pragma unroll
      for (int n = 0; n < 4; ++n) orow[n * 32] = acc[m][n][r] + bt;
    }
  }
}

extern "C" void kernel_launch(void* const* d_in, const int* in_sizes, int n_in,
                              void* d_out, int out_size, void* d_ws, size_t ws_size,
                              hipStream_t stream) {
  const float* hs   = (const float*)d_in[0];
  const float* W    = (const float*)d_in[1];
  const float* bias = (const float*)d_in[2];

  unsigned short* X = (unsigned short*)d_ws;                 // B*L*D bf16
  unsigned short* P = X + (size_t)B_ * L_ * D_;              // T*B*L*D bf16

  const int nconv = (B_ * L_ * D_ / 4) / 256;                // 6144 blocks
  conv_kernel<<<nconv, 256, 0, stream>>>(hs, W, X, P);

  gemm_kernel<<<1024, 256, 0, stream>>>(X, P, bias, (float*)d_out);
}